// Round 2
// baseline (976.632 us; speedup 1.0000x reference)
//
#include <hip/hip_runtime.h>

#define B_ 2
#define H_ 16
#define S_ 2048
#define D_ 64
#define QB 32
#define KT 64
#define NT (S_ / KT)      // 32
#define NTHREADS 512
#define KP 4              // pad: row stride 68 f16 = 136 B = 34 dw -> 2-way banks (free)

typedef _Float16 f16;
typedef _Float16 f16x8 __attribute__((ext_vector_type(8)));
typedef _Float16 f16x2 __attribute__((ext_vector_type(2)));
typedef float f32x4 __attribute__((ext_vector_type(4)));

#define MFMA16(a, b, c) __builtin_amdgcn_mfma_f32_16x16x32_f16(a, b, c, 0, 0, 0)

__global__ __launch_bounds__(NTHREADS)
void attn_kernel(const float* __restrict__ q, const float* __restrict__ k,
                 const float* __restrict__ v, const int* __restrict__ mask,
                 float* __restrict__ out)
{
    // 35072 B total -> 4 blocks/CU (thread-capped), conflict-free strides
    __shared__ f16 Qsh[QB][D_ + KP];       // [q][d]
    __shared__ f16 Ksh[KT][D_ + KP];       // [key][d]   (sweep-2 only, single buffer)
    __shared__ f16 Vt [2][D_][KT + KP];    // [d][key]   transposed, double buffer
    __shared__ f16 Psh[QB][KT + KP];       // [q][key]   single buffer
    __shared__ float rowred[QB];
    __shared__ float rlsh[QB];

    const int tid  = threadIdx.x;
    const int wave = tid >> 6;
    const int lane = tid & 63;
    const int quad = lane >> 4;
    const int l16  = lane & 15;
    const int qi   = wave & 1;   // q 16-row half
    const int ni   = wave >> 1;  // key 16-col block / O d-col block

    const int qb = blockIdx.x;
    const int h  = blockIdx.y;
    const int b  = blockIdx.z;
    const int bh = b * H_ + h;

    const float* Qg = q + ((size_t)bh * S_ + (size_t)qb * QB) * D_;
    const float* Kg = k + (size_t)bh * S_ * D_;
    const float* Vg = v + (size_t)bh * S_ * D_;
    const int*   Mg = mask + ((size_t)b * S_ + (size_t)qb * QB) * S_;
    float* res_out  = out + ((size_t)bh * S_ + (size_t)qb * QB) * D_;
    float* attn_out = out + (size_t)B_ * H_ * S_ * D_
                          + ((size_t)bh * S_ + (size_t)qb * QB) * S_;

    if (tid < QB) rowred[tid] = 0.f;

    // ---- stage Q (scale 1/8 folded; exact in fp16). 256 threads, b128 writes ----
    if (tid < 256) {
        const int row = tid >> 3;
        const int c   = (tid & 7) * 8;
        const float4 q0 = *(const float4*)(Qg + row * D_ + c);
        const float4 q1 = *(const float4*)(Qg + row * D_ + c + 4);
        f16x8 o;
        o[0] = (f16)(q0.x * 0.125f); o[1] = (f16)(q0.y * 0.125f);
        o[2] = (f16)(q0.z * 0.125f); o[3] = (f16)(q0.w * 0.125f);
        o[4] = (f16)(q1.x * 0.125f); o[5] = (f16)(q1.y * 0.125f);
        o[6] = (f16)(q1.z * 0.125f); o[7] = (f16)(q1.w * 0.125f);
        *(f16x8*)&Qsh[row][c] = o;
    }
    __syncthreads();

    // hoisted A-fragments: A[m=l16][k=quad*8+j]
    const f16x8 a0 = *(const f16x8*)&Qsh[qi * 16 + l16][quad * 8];
    const f16x8 a1 = *(const f16x8*)&Qsh[qi * 16 + l16][32 + quad * 8];

    const int qrow0   = qi * 16 + quad * 4;
    const int colbase = ni * 16 + l16;
    const int* mp0 = Mg + (size_t)qrow0 * S_ + colbase;

    // ============ sweep 1: row sums of exp — NO LDS, NO BARRIERS ============
    // B-fragment is 32 B contiguous K per lane: load f32 direct, cvt in regs.
    float psum[4] = {0.f, 0.f, 0.f, 0.f};
    {
        const float* kr0 = Kg + (size_t)(ni * 16 + l16) * D_;
#pragma unroll 2
        for (int kt = 0; kt < NT; ++kt) {
            const float* kr = kr0 + (size_t)kt * KT * D_;
            const float4 x0 = *(const float4*)(kr + quad * 8);
            const float4 x1 = *(const float4*)(kr + quad * 8 + 4);
            const float4 x2 = *(const float4*)(kr + 32 + quad * 8);
            const float4 x3 = *(const float4*)(kr + 32 + quad * 8 + 4);
            const int* mp = mp0 + kt * KT;
            int m[4];
#pragma unroll
            for (int r = 0; r < 4; ++r) m[r] = mp[(size_t)r * S_];
            f16x8 b0, b1;
            b0[0] = (f16)x0.x; b0[1] = (f16)x0.y; b0[2] = (f16)x0.z; b0[3] = (f16)x0.w;
            b0[4] = (f16)x1.x; b0[5] = (f16)x1.y; b0[6] = (f16)x1.z; b0[7] = (f16)x1.w;
            b1[0] = (f16)x2.x; b1[1] = (f16)x2.y; b1[2] = (f16)x2.z; b1[3] = (f16)x2.w;
            b1[4] = (f16)x3.x; b1[5] = (f16)x3.y; b1[6] = (f16)x3.z; b1[7] = (f16)x3.w;
            f32x4 c = {0.f, 0.f, 0.f, 0.f};
            c = MFMA16(a0, b0, c);
            c = MFMA16(a1, b1, c);
#pragma unroll
            for (int r = 0; r < 4; ++r)
                psum[r] += (m[r] == 1) ? 0.f : __expf(c[r]);
        }
    }

    // reduce psum across the 16 column-lanes of each quad
#pragma unroll
    for (int r = 0; r < 4; ++r) {
        psum[r] += __shfl_xor(psum[r], 1);
        psum[r] += __shfl_xor(psum[r], 2);
        psum[r] += __shfl_xor(psum[r], 4);
        psum[r] += __shfl_xor(psum[r], 8);
    }
    if (l16 == 0) {
#pragma unroll
        for (int r = 0; r < 4; ++r) atomicAdd(&rowred[qrow0 + r], psum[r]);
    }
    __syncthreads();
    if (tid < QB) rlsh[tid] = 1.0f / rowred[tid];
    __syncthreads();
    float rlq[4];
#pragma unroll
    for (int r = 0; r < 4; ++r) rlq[r] = rlsh[qrow0 + r];

    // ============ sweep 2: write attn, accumulate O — 2 barriers/tile ============
    // staging coordinates
    const int skk = tid >> 3;        // K: row (0..63)
    const int sd0 = (tid & 7) * 8;   // K: d-col
    const int vkp = tid & 31;        // V: key-pair (rows 2*vkp, 2*vkp+1)
    const int vd0 = (tid >> 5) * 4;  // V: d-quad

    // prologue: prefetch tile 0 into regs
    float4 kx0, kx1, vy0, vy1;
    int mnext[4];
    {
        const float* srck = Kg + (size_t)skk * D_ + sd0;
        kx0 = *(const float4*)(srck);
        kx1 = *(const float4*)(srck + 4);
        const float* srcv = Vg + (size_t)(2 * vkp) * D_ + vd0;
        vy0 = *(const float4*)(srcv);
        vy1 = *(const float4*)(srcv + D_);
#pragma unroll
        for (int r = 0; r < 4; ++r) mnext[r] = mp0[(size_t)r * S_];
    }

    f32x4 oacc = {0.f, 0.f, 0.f, 0.f};
    float* ap0 = attn_out + (size_t)qrow0 * S_ + colbase;

    for (int kt = 0; kt < NT; ++kt) {
        const int buf = kt & 1;
        const int ktn = (kt + 1 < NT) ? kt + 1 : kt;   // clamped (last redundant)

        // ---- commit prefetched K -> Ksh (single buf: prior readers pre-B2(kt-1)),
        //      V -> Vt[buf] (other buf read in kt-1, separated by B1(kt)) ----
        {
            f16x8 o;
            o[0] = (f16)kx0.x; o[1] = (f16)kx0.y; o[2] = (f16)kx0.z; o[3] = (f16)kx0.w;
            o[4] = (f16)kx1.x; o[5] = (f16)kx1.y; o[6] = (f16)kx1.z; o[7] = (f16)kx1.w;
            *(f16x8*)&Ksh[skk][sd0] = o;
        }
#pragma unroll
        for (int j = 0; j < 4; ++j) {
            f16x2 pr;
            pr[0] = (f16)((&vy0.x)[j]);
            pr[1] = (f16)((&vy1.x)[j]);
            *(f16x2*)&Vt[buf][vd0 + j][2 * vkp] = pr;   // transposed store
        }
        __syncthreads();   // B1: Ksh(kt), Vt[buf](kt) visible

        // ---- QK fragments, then issue next-tile prefetch (hidden under compute) ----
        const f16x8 b0 = *(const f16x8*)&Ksh[ni * 16 + l16][quad * 8];
        const f16x8 b1 = *(const f16x8*)&Ksh[ni * 16 + l16][32 + quad * 8];
        {
            const float* srck = Kg + ((size_t)(ktn * KT + skk)) * D_ + sd0;
            kx0 = *(const float4*)(srck);
            kx1 = *(const float4*)(srck + 4);
            const float* srcv = Vg + ((size_t)(ktn * KT + 2 * vkp)) * D_ + vd0;
            vy0 = *(const float4*)(srcv);
            vy1 = *(const float4*)(srcv + D_);
        }
        int mcur[4];
#pragma unroll
        for (int r = 0; r < 4; ++r) mcur[r] = mnext[r];
        const int* mpn = mp0 + ktn * KT;
#pragma unroll
        for (int r = 0; r < 4; ++r) mnext[r] = mpn[(size_t)r * S_];

        f32x4 c = {0.f, 0.f, 0.f, 0.f};
        c = MFMA16(a0, b0, c);
        c = MFMA16(a1, b1, c);
        float* ap = ap0 + kt * KT;
#pragma unroll
        for (int r = 0; r < 4; ++r) {
            const float e = (mcur[r] == 1) ? 0.f : __expf(c[r]);
            const float p = e * rlq[r];
            ap[(size_t)r * S_] = p;                 // attn output
            Psh[qrow0 + r][colbase] = (f16)p;       // C-layout -> A-layout via LDS
        }
        __syncthreads();   // B2: Psh visible; Ksh readers done

        // ---- PV: all-b128, conflict-free (stride 34 dw) ----
        const f16x8 pa0 = *(const f16x8*)&Psh[qi * 16 + l16][quad * 8];
        const f16x8 pa1 = *(const f16x8*)&Psh[qi * 16 + l16][32 + quad * 8];
        const f16x8 vb0 = *(const f16x8*)&Vt[buf][colbase][quad * 8];
        const f16x8 vb1 = *(const f16x8*)&Vt[buf][colbase][32 + quad * 8];
        oacc = MFMA16(pa0, vb0, oacc);
        oacc = MFMA16(pa1, vb1, oacc);
    }

    // res: rows qrow0+r, col = colbase (1/l already folded into P)
#pragma unroll
    for (int r = 0; r < 4; ++r)
        res_out[(size_t)(qrow0 + r) * D_ + colbase] = oacc[r];
}

extern "C" void kernel_launch(void* const* d_in, const int* in_sizes, int n_in,
                              void* d_out, int out_size, void* d_ws, size_t ws_size,
                              hipStream_t stream) {
    (void)in_sizes; (void)n_in; (void)out_size; (void)d_ws; (void)ws_size;
    const float* q   = (const float*)d_in[0];
    const float* k   = (const float*)d_in[1];
    const float* v   = (const float*)d_in[2];
    const int*  mask = (const int*)d_in[3];
    float* out = (float*)d_out;
    dim3 grid(S_ / QB, H_, B_);   // qblock fastest -> K/V L2 reuse
    attn_kernel<<<grid, dim3(NTHREADS), 0, stream>>>(q, k, v, mask, out);
}

// Round 3
// 947.496 us; speedup vs baseline: 1.0308x; 1.0308x over previous
//
#include <hip/hip_runtime.h>

#define B_ 2
#define H_ 16
#define S_ 2048
#define D_ 64
#define QB 32
#define KT 64
#define NT (S_ / KT)      // 32
#define NTHREADS 512
#define KP 4              // row stride 68 f16 = 136 B = 34 dw -> conflict-free (proven R2)

typedef _Float16 f16;
typedef _Float16 f16x8 __attribute__((ext_vector_type(8)));
typedef _Float16 f16x4 __attribute__((ext_vector_type(4)));
typedef _Float16 f16x2 __attribute__((ext_vector_type(2)));
typedef float f32x4 __attribute__((ext_vector_type(4)));

#define MFMA32(a, b, c) __builtin_amdgcn_mfma_f32_16x16x32_f16(a, b, c, 0, 0, 0)
#define MFMA16(a, b, c) __builtin_amdgcn_mfma_f32_16x16x16f16(a, b, c, 0, 0, 0)

__device__ __forceinline__ f16x8 pack8(const float4 x0, const float4 x1) {
    f16x8 o;
    o[0] = (f16)x0.x; o[1] = (f16)x0.y; o[2] = (f16)x0.z; o[3] = (f16)x0.w;
    o[4] = (f16)x1.x; o[5] = (f16)x1.y; o[6] = (f16)x1.z; o[7] = (f16)x1.w;
    return o;
}

__global__ __launch_bounds__(NTHREADS)
void attn_kernel(const float* __restrict__ q, const float* __restrict__ k,
                 const float* __restrict__ v, const int* __restrict__ mask,
                 float* __restrict__ out)
{
    // [0]=K[key][d], [1]=V^T[d][key]; each double-buffered. 34816 B + 256 B.
    __shared__ __align__(16) f16 KVt[2][2][KT][D_ + KP];
    __shared__ float rowred[QB];
    __shared__ float rlsh[QB];

    const int tid  = threadIdx.x;
    const int lane = tid & 63;
    const int wave = tid >> 6;
    const int quad = lane >> 4;
    const int l16  = lane & 15;
    const int qi   = wave & 1;   // q 16-row half
    const int ni   = wave >> 1;  // key 16-block owned by this wave

    // T1: XCD-chunk swizzle (2048 blocks = 8 XCDs x 256): each XCD gets 4 whole heads
    const int bid = blockIdx.x;
    const int bsw = ((bid & 7) << 8) | (bid >> 3);
    const int qb = bsw & 63;
    const int h  = (bsw >> 6) & 15;
    const int b  = bsw >> 10;
    const int bh = b * H_ + h;

    const float* Qg = q + ((size_t)bh * S_ + (size_t)qb * QB) * D_;
    const float* Kg = k + (size_t)bh * S_ * D_;
    const float* Vg = v + (size_t)bh * S_ * D_;
    float* res_out  = out + ((size_t)bh * S_ + (size_t)qb * QB) * D_;
    float* attn_out = out + (size_t)B_ * H_ * S_ * D_
                          + ((size_t)bh * S_ + (size_t)qb * QB) * S_;

    // per-lane mask / attn pointers (swapped layout: lane owns q-row qi*16+l16,
    // keys ni*16+quad*4..+3  -> int4 mask load, float4 attn store)
    const int* mpl = mask + (size_t)b * S_ * S_
                   + (size_t)(qb * QB + qi * 16 + l16) * S_ + ni * 16 + quad * 4;
    float* aprow = attn_out + (size_t)(qi * 16 + l16) * S_ + ni * 16 + quad * 4;

    // ---- Q fragments direct from global (once per block; no LDS round-trip) ----
    // lane: Q[q=qi*16+l16][d=quad*8+j] (+32), scale 1/8 folded (exact in fp16)
    f16x8 a0, a1;
    {
        const float* qrow = Qg + (size_t)(qi * 16 + l16) * D_;
        const float4 q0 = *(const float4*)(qrow + quad * 8);
        const float4 q1 = *(const float4*)(qrow + quad * 8 + 4);
        const float4 q2 = *(const float4*)(qrow + 32 + quad * 8);
        const float4 q3 = *(const float4*)(qrow + 32 + quad * 8 + 4);
        a0[0]=(f16)(q0.x*0.125f); a0[1]=(f16)(q0.y*0.125f); a0[2]=(f16)(q0.z*0.125f); a0[3]=(f16)(q0.w*0.125f);
        a0[4]=(f16)(q1.x*0.125f); a0[5]=(f16)(q1.y*0.125f); a0[6]=(f16)(q1.z*0.125f); a0[7]=(f16)(q1.w*0.125f);
        a1[0]=(f16)(q2.x*0.125f); a1[1]=(f16)(q2.y*0.125f); a1[2]=(f16)(q2.z*0.125f); a1[3]=(f16)(q2.w*0.125f);
        a1[4]=(f16)(q3.x*0.125f); a1[5]=(f16)(q3.y*0.125f); a1[6]=(f16)(q3.z*0.125f); a1[7]=(f16)(q3.w*0.125f);
    }

    // staging coordinates (coalesced, conflict-free: proven in R2)
    const int skk = tid >> 3;        // K: row (0..63)
    const int sd0 = (tid & 7) * 8;   // K: d-col
    const int vkp = tid & 31;        // V: key-pair (rows 2*vkp, 2*vkp+1)
    const int vd0 = (tid >> 5) * 4;  // V: d-quad

    // ================= sweep 1: row sums of exp (1 barrier / tile) =================
    {
        const float* srck = Kg + (size_t)skk * D_ + sd0;
        *(f16x8*)&KVt[0][0][skk][sd0] =
            pack8(*(const float4*)srck, *(const float4*)(srck + 4));
    }
    if (tid < QB) rowred[tid] = 0.f;
    __syncthreads();

    float psum = 0.f;
    for (int kt = 0; kt < NT; ++kt) {
        const int cur = kt & 1;
        const int ktn = (kt + 1 < NT) ? kt + 1 : kt;   // clamped (last redundant)
        // issue next-tile K loads now (consumed after compute)
        const float* srck = Kg + ((size_t)(ktn * KT + skk)) * D_ + sd0;
        const float4 x0 = *(const float4*)(srck);
        const float4 x1 = *(const float4*)(srck + 4);
        const int4 mm = *(const int4*)(mpl + kt * KT);

        // swapped QK: c = K * Q -> lane holds S^T[key=ni*16+quad*4+r][q=qi*16+l16]
        const f16x8 b0 = *(const f16x8*)&KVt[0][cur][ni * 16 + l16][quad * 8];
        const f16x8 b1 = *(const f16x8*)&KVt[0][cur][ni * 16 + l16][32 + quad * 8];
        f32x4 c = {0.f, 0.f, 0.f, 0.f};
        c = MFMA32(b0, a0, c);
        c = MFMA32(b1, a1, c);
        psum += (mm.x == 1) ? 0.f : __expf(c[0]);
        psum += (mm.y == 1) ? 0.f : __expf(c[1]);
        psum += (mm.z == 1) ? 0.f : __expf(c[2]);
        psum += (mm.w == 1) ? 0.f : __expf(c[3]);

        *(f16x8*)&KVt[0][cur ^ 1][skk][sd0] = pack8(x0, x1);
        __syncthreads();
    }
    // lane psum covers keys {ni*16+quad*4..+3} summed over tiles; combine quads, then waves
    psum += __shfl_xor(psum, 16);
    psum += __shfl_xor(psum, 32);
    if (lane < 16) atomicAdd(&rowred[qi * 16 + l16], psum);
    __syncthreads();
    if (tid < QB) rlsh[tid] = 1.0f / rowred[tid];
    __syncthreads();
    const float rl = rlsh[qi * 16 + l16];

    // ================= sweep 2: attn write + partial-O accumulate (1 barrier / tile) =================
    {
        const float* srck = Kg + (size_t)skk * D_ + sd0;
        *(f16x8*)&KVt[0][0][skk][sd0] =
            pack8(*(const float4*)srck, *(const float4*)(srck + 4));
        const float* srcv = Vg + (size_t)(2 * vkp) * D_ + vd0;
        const float4 y0 = *(const float4*)(srcv);
        const float4 y1 = *(const float4*)(srcv + D_);
#pragma unroll
        for (int j = 0; j < 4; ++j) {
            f16x2 pr; pr[0] = (f16)((&y0.x)[j]); pr[1] = (f16)((&y1.x)[j]);
            *(f16x2*)&KVt[1][0][vd0 + j][2 * vkp] = pr;
        }
    }
    __syncthreads();

    f32x4 oacc0 = {0.f,0.f,0.f,0.f}, oacc1 = {0.f,0.f,0.f,0.f};
    f32x4 oacc2 = {0.f,0.f,0.f,0.f}, oacc3 = {0.f,0.f,0.f,0.f};

    for (int kt = 0; kt < NT; ++kt) {
        const int cur = kt & 1;
        const int ktn = (kt + 1 < NT) ? kt + 1 : kt;

        // issue next-tile K,V loads (held in regs until commit below)
        const float* srck = Kg + ((size_t)(ktn * KT + skk)) * D_ + sd0;
        const float4 x0 = *(const float4*)(srck);
        const float4 x1 = *(const float4*)(srck + 4);
        const float* srcv = Vg + ((size_t)(ktn * KT + 2 * vkp)) * D_ + vd0;
        const float4 y0 = *(const float4*)(srcv);
        const float4 y1 = *(const float4*)(srcv + D_);
        const int4 mm = *(const int4*)(mpl + kt * KT);

        // swapped scores
        const f16x8 b0 = *(const f16x8*)&KVt[0][cur][ni * 16 + l16][quad * 8];
        const f16x8 b1 = *(const f16x8*)&KVt[0][cur][ni * 16 + l16][32 + quad * 8];
        f32x4 c = {0.f, 0.f, 0.f, 0.f};
        c = MFMA32(b0, a0, c);
        c = MFMA32(b1, a1, c);
        const float p0 = (mm.x == 1) ? 0.f : __expf(c[0]) * rl;
        const float p1 = (mm.y == 1) ? 0.f : __expf(c[1]) * rl;
        const float p2 = (mm.z == 1) ? 0.f : __expf(c[2]) * rl;
        const float p3 = (mm.w == 1) ? 0.f : __expf(c[3]) * rl;
        *(float4*)(aprow + (size_t)kt * KT) = make_float4(p0, p1, p2, p3);  // vectorized attn

        // P^T is already the mfma16 B-fragment: B[k=quad*4+r][n=q=l16]
        f16x4 pb;
        pb[0] = (f16)p0; pb[1] = (f16)p1; pb[2] = (f16)p2; pb[3] = (f16)p3;

        // O^T[d][q] partial over this wave's 16 keys, all 4 d-blocks (b64 V^T reads)
        const f16x4 vb0 = *(const f16x4*)&KVt[1][cur][ 0 + l16][ni * 16 + quad * 4];
        const f16x4 vb1 = *(const f16x4*)&KVt[1][cur][16 + l16][ni * 16 + quad * 4];
        const f16x4 vb2 = *(const f16x4*)&KVt[1][cur][32 + l16][ni * 16 + quad * 4];
        const f16x4 vb3 = *(const f16x4*)&KVt[1][cur][48 + l16][ni * 16 + quad * 4];
        oacc0 = MFMA16(vb0, pb, oacc0);
        oacc1 = MFMA16(vb1, pb, oacc1);
        oacc2 = MFMA16(vb2, pb, oacc2);
        oacc3 = MFMA16(vb3, pb, oacc3);

        // commit prefetched K,V to the other buffer
        *(f16x8*)&KVt[0][cur ^ 1][skk][sd0] = pack8(x0, x1);
#pragma unroll
        for (int j = 0; j < 4; ++j) {
            f16x2 pr; pr[0] = (f16)((&y0.x)[j]); pr[1] = (f16)((&y1.x)[j]);
            *(f16x2*)&KVt[1][cur ^ 1][vd0 + j][2 * vkp] = pr;
        }
        __syncthreads();
    }

    // ===== epilogue: reduce partial O across the 4 ni-waves (LDS aliased onto KVt) =====
    // lane holds O[q=qi*16+l16][d=db*16+quad*4+r] in oacc{db}[r]
    float* O = (float*)&KVt[0][0][0][0];   // [4 regions][2 qi][16 q][68] f32 = 34816 B
    {
        const int base = ((ni * 2 + qi) * 16 + l16) * 68 + quad * 4;
        *(f32x4*)&O[base +  0] = oacc0;
        *(f32x4*)&O[base + 16] = oacc1;
        *(f32x4*)&O[base + 32] = oacc2;
        *(f32x4*)&O[base + 48] = oacc3;
    }
    __syncthreads();
    {
        const int qi2 = tid >> 8;          // 512 = 2 * 16 * 16 exactly
        const int q2  = (tid >> 4) & 15;
        const int dc  = tid & 15;
        const int off = (qi2 * 16 + q2) * 68 + dc * 4;
        f32x4 s = *(f32x4*)&O[0 * 2176 + off];
        s = s + *(f32x4*)&O[1 * 2176 + off];
        s = s + *(f32x4*)&O[2 * 2176 + off];
        s = s + *(f32x4*)&O[3 * 2176 + off];
        *(f32x4*)(res_out + (size_t)(qi2 * 16 + q2) * D_ + dc * 4) = s;
    }
}

extern "C" void kernel_launch(void* const* d_in, const int* in_sizes, int n_in,
                              void* d_out, int out_size, void* d_ws, size_t ws_size,
                              hipStream_t stream) {
    (void)in_sizes; (void)n_in; (void)out_size; (void)d_ws; (void)ws_size;
    const float* q   = (const float*)d_in[0];
    const float* k   = (const float*)d_in[1];
    const float* v   = (const float*)d_in[2];
    const int*  mask = (const int*)d_in[3];
    float* out = (float*)d_out;
    attn_kernel<<<dim3(S_ / QB * H_ * B_), dim3(NTHREADS), 0, stream>>>(q, k, v, mask, out);
}

// Round 4
// 870.879 us; speedup vs baseline: 1.1214x; 1.0880x over previous
//
#include <hip/hip_runtime.h>

#define B_ 2
#define H_ 16
#define S_ 2048
#define D_ 64
#define QB 32
#define KT 64
#define NTHREADS 512
#define KP 4   // row stride 68 f16 = 136 B = 34 dw -> measured conflict-free (R2: 0 conflicts)

typedef _Float16 f16;
typedef _Float16 f16x8 __attribute__((ext_vector_type(8)));
typedef _Float16 f16x4 __attribute__((ext_vector_type(4)));
typedef _Float16 f16x2 __attribute__((ext_vector_type(2)));
typedef float f32x4 __attribute__((ext_vector_type(4)));

#define MFMA16(a, b, c) __builtin_amdgcn_mfma_f32_16x16x32_f16(a, b, c, 0, 0, 0)

__global__ __launch_bounds__(NTHREADS)
void attn_kernel(const float* __restrict__ q, const float* __restrict__ k,
                 const float* __restrict__ v, const int* __restrict__ mask,
                 float* __restrict__ out)
{
    // ~26.4 KB total -> 4 blocks/CU (thread-capped), all strides 34 dw (conflict-free)
    __shared__ f16 Qsh[QB][D_ + KP];    // [q][d]
    __shared__ f16 Ksh[KT][D_ + KP];    // [key][d]
    __shared__ f16 Vt [D_][KT + KP];    // [d][key]  TRANSPOSED -> b128 B-frag reads
    __shared__ f16 Psh[QB][KT + KP];    // [q][key]
    __shared__ float rowred[QB];
    __shared__ float rlsh[QB];

    const int tid  = threadIdx.x;
    const int wave = tid >> 6;
    const int lane = tid & 63;
    const int quad = lane >> 4;
    const int l16  = lane & 15;
    const int qi   = wave & 1;   // q 16-row half
    const int ni   = wave >> 1;  // score col / O d-col 16-block

    const int qb = blockIdx.x;
    const int h  = blockIdx.y;
    const int b  = blockIdx.z;
    const int bh = b * H_ + h;

    const float* Qg = q + ((size_t)bh * S_ + (size_t)qb * QB) * D_;
    const float* Kg = k + (size_t)bh * S_ * D_;
    const float* Vg = v + (size_t)bh * S_ * D_;
    const int*   Mg = mask + ((size_t)b * S_ + (size_t)qb * QB) * S_;
    float* res_out  = out + ((size_t)bh * S_ + (size_t)qb * QB) * D_;
    float* attn_out = out + (size_t)B_ * H_ * S_ * D_
                          + ((size_t)bh * S_ + (size_t)qb * QB) * S_;

    if (tid < QB) rowred[tid] = 0.f;

    // ---- stage Q (scale 1/8 folded in; exact in fp16: power of 2) ----
    {
        const int row = tid >> 4;
        const int c4  = (tid & 15) * 4;
        const float4 qv = *(const float4*)(Qg + row * D_ + c4);
        f16x4 o;
        o[0] = (f16)(qv.x * 0.125f); o[1] = (f16)(qv.y * 0.125f);
        o[2] = (f16)(qv.z * 0.125f); o[3] = (f16)(qv.w * 0.125f);
        *(f16x4*)&Qsh[row][c4] = o;
    }
    __syncthreads();

    // hoisted A-fragments: A[m=l16][k=quad*8+j], K=64 -> two frags
    const int qrow0 = qi * 16 + quad * 4;
    const f16x8 a0 = *(const f16x8*)&Qsh[qi * 16 + l16][quad * 8];
    const f16x8 a1 = *(const f16x8*)&Qsh[qi * 16 + l16][32 + quad * 8];

    const int colbase = ni * 16 + l16;
    const int* mp0 = Mg + (size_t)qrow0 * S_ + colbase;

    const int skk = tid >> 3;        // K staging row (0..63)
    const int sd0 = (tid & 7) * 8;   // K staging d-col
    const int vkp = tid & 31;        // V staging: key-pair (rows 2*vkp, 2*vkp+1)
    const int vd0 = (tid >> 5) * 4;  // V staging: d-quad

    // ================= sweep 1: row sums of exp =================
    float psum[4] = {0.f, 0.f, 0.f, 0.f};
    for (int kt = 0; kt < S_ / KT; ++kt) {
        {
            const float* src = Kg + ((size_t)(kt * KT + skk)) * D_ + sd0;
            const float4 x0 = *(const float4*)(src);
            const float4 x1 = *(const float4*)(src + 4);
            f16x8 o;
            o[0] = (f16)x0.x; o[1] = (f16)x0.y; o[2] = (f16)x0.z; o[3] = (f16)x0.w;
            o[4] = (f16)x1.x; o[5] = (f16)x1.y; o[6] = (f16)x1.z; o[7] = (f16)x1.w;
            *(f16x8*)&Ksh[skk][sd0] = o;
        }
        __syncthreads();
        const f16x8 b0 = *(const f16x8*)&Ksh[ni * 16 + l16][quad * 8];
        const f16x8 b1 = *(const f16x8*)&Ksh[ni * 16 + l16][32 + quad * 8];
        f32x4 c = {0.f, 0.f, 0.f, 0.f};
        c = MFMA16(a0, b0, c);
        c = MFMA16(a1, b1, c);
        const int* mp = mp0 + kt * KT;
#pragma unroll
        for (int r = 0; r < 4; ++r) {
            const int m = mp[(size_t)r * S_];
            const float e = (m == 1) ? 0.f : __expf(c[r]);
            psum[r] += e;
        }
        __syncthreads();
    }

    // reduce psum across the 16 column-lanes of each quad
#pragma unroll
    for (int r = 0; r < 4; ++r) {
        psum[r] += __shfl_xor(psum[r], 1);
        psum[r] += __shfl_xor(psum[r], 2);
        psum[r] += __shfl_xor(psum[r], 4);
        psum[r] += __shfl_xor(psum[r], 8);
    }
    if (l16 == 0) {
#pragma unroll
        for (int r = 0; r < 4; ++r) atomicAdd(&rowred[qrow0 + r], psum[r]);
    }
    __syncthreads();
    if (tid < QB) rlsh[tid] = 1.0f / rowred[tid];
    __syncthreads();
    float rlq[4];
#pragma unroll
    for (int r = 0; r < 4; ++r) rlq[r] = rlsh[qrow0 + r];

    // ================= sweep 2: write attn, accumulate O =================
    f32x4 oacc = {0.f, 0.f, 0.f, 0.f};
    float* ap0 = attn_out + (size_t)qrow0 * S_ + colbase;

    for (int kt = 0; kt < S_ / KT; ++kt) {
        {
            const float* srck = Kg + ((size_t)(kt * KT + skk)) * D_ + sd0;
            const float4 x0 = *(const float4*)(srck);
            const float4 x1 = *(const float4*)(srck + 4);
            f16x8 o;
            o[0] = (f16)x0.x; o[1] = (f16)x0.y; o[2] = (f16)x0.z; o[3] = (f16)x0.w;
            o[4] = (f16)x1.x; o[5] = (f16)x1.y; o[6] = (f16)x1.z; o[7] = (f16)x1.w;
            *(f16x8*)&Ksh[skk][sd0] = o;

            // V: transposed store (R2-proven conflict-free pair-pack)
            const float* srcv = Vg + ((size_t)(kt * KT + 2 * vkp)) * D_ + vd0;
            const float4 y0 = *(const float4*)(srcv);        // row 2*vkp
            const float4 y1 = *(const float4*)(srcv + D_);   // row 2*vkp+1
#pragma unroll
            for (int j = 0; j < 4; ++j) {
                f16x2 pr;
                pr[0] = (f16)((&y0.x)[j]);
                pr[1] = (f16)((&y1.x)[j]);
                *(f16x2*)&Vt[vd0 + j][2 * vkp] = pr;
            }
        }
        __syncthreads();
        // scores (recompute)
        const f16x8 b0 = *(const f16x8*)&Ksh[ni * 16 + l16][quad * 8];
        const f16x8 b1 = *(const f16x8*)&Ksh[ni * 16 + l16][32 + quad * 8];
        f32x4 c = {0.f, 0.f, 0.f, 0.f};
        c = MFMA16(a0, b0, c);
        c = MFMA16(a1, b1, c);
        const int* mp = mp0 + kt * KT;
        float* ap = ap0 + kt * KT;
#pragma unroll
        for (int r = 0; r < 4; ++r) {
            const int m = mp[(size_t)r * S_];
            const float e = (m == 1) ? 0.f : __expf(c[r]);
            const float p = e * rlq[r];
            ap[(size_t)r * S_] = p;                 // attn output
            Psh[qrow0 + r][colbase] = (f16)p;       // C-layout -> A-layout via LDS
        }
        __syncthreads();
        // PV: all-b128 fragment reads (Vt transposed, stride 34 dw)
        const f16x8 pa0 = *(const f16x8*)&Psh[qi * 16 + l16][quad * 8];
        const f16x8 pa1 = *(const f16x8*)&Psh[qi * 16 + l16][32 + quad * 8];
        const int dcol = ni * 16 + l16;
        const f16x8 vb0 = *(const f16x8*)&Vt[dcol][quad * 8];
        const f16x8 vb1 = *(const f16x8*)&Vt[dcol][32 + quad * 8];
        oacc = MFMA16(pa0, vb0, oacc);
        oacc = MFMA16(pa1, vb1, oacc);
        __syncthreads();
    }

    // res: rows qrow0+r, col = ni*16+l16 (1/l already folded into P)
#pragma unroll
    for (int r = 0; r < 4; ++r)
        res_out[(size_t)(qrow0 + r) * D_ + ni * 16 + l16] = oacc[r];
}

extern "C" void kernel_launch(void* const* d_in, const int* in_sizes, int n_in,
                              void* d_out, int out_size, void* d_ws, size_t ws_size,
                              hipStream_t stream) {
    (void)in_sizes; (void)n_in; (void)out_size; (void)d_ws; (void)ws_size;
    const float* q   = (const float*)d_in[0];
    const float* k   = (const float*)d_in[1];
    const float* v   = (const float*)d_in[2];
    const int*  mask = (const int*)d_in[3];
    float* out = (float*)d_out;
    dim3 grid(S_ / QB, H_, B_);   // qblock fastest -> K/V L2 reuse; mask from L3
    attn_kernel<<<grid, dim3(NTHREADS), 0, stream>>>(q, k, v, mask, out);
}

// Round 5
// 836.684 us; speedup vs baseline: 1.1673x; 1.0409x over previous
//
#include <hip/hip_runtime.h>

#define B_ 2
#define H_ 16
#define S_ 2048
#define D_ 64
#define QB 64
#define KT 64
#define NTHREADS 512

typedef _Float16 f16;
typedef _Float16 f16x8 __attribute__((ext_vector_type(8)));
typedef _Float16 f16x4 __attribute__((ext_vector_type(4)));
typedef _Float16 f16x2 __attribute__((ext_vector_type(2)));
typedef float f32x4 __attribute__((ext_vector_type(4)));

#define MFMA16(a, b, c) __builtin_amdgcn_mfma_f32_16x16x32_f16(a, b, c, 0, 0, 0)

__global__ __launch_bounds__(NTHREADS)
void attn_kernel(const float* __restrict__ q, const float* __restrict__ k,
                 const float* __restrict__ v, const int* __restrict__ mask,
                 float* __restrict__ out)
{
    // ~36.6 KB -> 4 blocks/CU (thread-capped). R0-proven layouts/pads.
    __shared__ f16 Qsh[QB][D_ + 8];    // 64 x 72
    __shared__ f16 Ksh[KT][D_ + 8];    // 64 x 72
    __shared__ f16 Vsh[KT][D_ + 2];    // 64 x 66 row-major (R0)
    __shared__ f16 Psh[QB][KT + 8];    // 64 x 72
    __shared__ float rowred[QB];
    __shared__ float rlsh[QB];

    const int tid  = threadIdx.x;
    const int wave = tid >> 6;
    const int lane = tid & 63;
    const int quad = lane >> 4;
    const int l16  = lane & 15;
    const int qi   = wave & 3;   // q 16-row block (0..3)
    const int ni   = wave >> 2;  // key/d 16-block pair selector (0..1): cols ni*16 and 32+ni*16

    const int qb = blockIdx.x;
    const int h  = blockIdx.y;
    const int b  = blockIdx.z;
    const int bh = b * H_ + h;

    const float* Qg = q + ((size_t)bh * S_ + (size_t)qb * QB) * D_;
    const float* Kg = k + (size_t)bh * S_ * D_;
    const float* Vg = v + (size_t)bh * S_ * D_;
    const int*   Mg = mask + ((size_t)b * S_ + (size_t)qb * QB) * S_;
    float* res_out  = out + ((size_t)bh * S_ + (size_t)qb * QB) * D_;
    float* attn_out = out + (size_t)B_ * H_ * S_ * D_
                          + ((size_t)bh * S_ + (size_t)qb * QB) * S_;

    if (tid < QB) rowred[tid] = 0.f;

    // ---- stage Q (scale 1/8 folded; exact in fp16). 512 thr x 8 floats = 64x64 ----
    {
        const int row = tid >> 3;
        const int c   = (tid & 7) * 8;
        const float4 q0 = *(const float4*)(Qg + row * D_ + c);
        const float4 q1 = *(const float4*)(Qg + row * D_ + c + 4);
        f16x8 o;
        o[0] = (f16)(q0.x * 0.125f); o[1] = (f16)(q0.y * 0.125f);
        o[2] = (f16)(q0.z * 0.125f); o[3] = (f16)(q0.w * 0.125f);
        o[4] = (f16)(q1.x * 0.125f); o[5] = (f16)(q1.y * 0.125f);
        o[6] = (f16)(q1.z * 0.125f); o[7] = (f16)(q1.w * 0.125f);
        *(f16x8*)&Qsh[row][c] = o;
    }
    __syncthreads();

    // hoisted A-fragments: A[m=l16][k=quad*8+j], K=64 -> two frags
    const int qrow0 = qi * 16 + quad * 4;
    const f16x8 a0 = *(const f16x8*)&Qsh[qi * 16 + l16][quad * 8];
    const f16x8 a1 = *(const f16x8*)&Qsh[qi * 16 + l16][32 + quad * 8];

    const int colbase = ni * 16 + l16;          // col-block A; block B at +32
    const int* mp0 = Mg + (size_t)qrow0 * S_ + colbase;

    const int skk = tid >> 3;        // staging row (0..63)
    const int sd0 = (tid & 7) * 8;   // staging d-col

    // ================= sweep 1: row sums of exp =================
    float psum[4] = {0.f, 0.f, 0.f, 0.f};
    for (int kt = 0; kt < S_ / KT; ++kt) {
        {
            const float* src = Kg + ((size_t)(kt * KT + skk)) * D_ + sd0;
            const float4 x0 = *(const float4*)(src);
            const float4 x1 = *(const float4*)(src + 4);
            f16x8 o;
            o[0] = (f16)x0.x; o[1] = (f16)x0.y; o[2] = (f16)x0.z; o[3] = (f16)x0.w;
            o[4] = (f16)x1.x; o[5] = (f16)x1.y; o[6] = (f16)x1.z; o[7] = (f16)x1.w;
            *(f16x8*)&Ksh[skk][sd0] = o;
        }
        __syncthreads();
        const f16x8 b0a = *(const f16x8*)&Ksh[colbase][quad * 8];
        const f16x8 b0b = *(const f16x8*)&Ksh[colbase][32 + quad * 8];
        const f16x8 b1a = *(const f16x8*)&Ksh[32 + colbase][quad * 8];
        const f16x8 b1b = *(const f16x8*)&Ksh[32 + colbase][32 + quad * 8];
        f32x4 c0 = {0.f, 0.f, 0.f, 0.f};
        c0 = MFMA16(a0, b0a, c0);
        c0 = MFMA16(a1, b0b, c0);
        f32x4 c1 = {0.f, 0.f, 0.f, 0.f};
        c1 = MFMA16(a0, b1a, c1);
        c1 = MFMA16(a1, b1b, c1);
        const int* mp = mp0 + kt * KT;
#pragma unroll
        for (int r = 0; r < 4; ++r) {
            const int m0 = mp[(size_t)r * S_];
            const int m1 = mp[(size_t)r * S_ + 32];
            psum[r] += (m0 == 1) ? 0.f : __expf(c0[r]);
            psum[r] += (m1 == 1) ? 0.f : __expf(c1[r]);
        }
        __syncthreads();
    }

    // reduce psum across the 16 column-lanes of each quad
#pragma unroll
    for (int r = 0; r < 4; ++r) {
        psum[r] += __shfl_xor(psum[r], 1);
        psum[r] += __shfl_xor(psum[r], 2);
        psum[r] += __shfl_xor(psum[r], 4);
        psum[r] += __shfl_xor(psum[r], 8);
    }
    if (l16 == 0) {
#pragma unroll
        for (int r = 0; r < 4; ++r) atomicAdd(&rowred[qrow0 + r], psum[r]);
    }
    __syncthreads();
    if (tid < QB) rlsh[tid] = 1.0f / rowred[tid];
    __syncthreads();
    float rlq[4];
#pragma unroll
    for (int r = 0; r < 4; ++r) rlq[r] = rlsh[qrow0 + r];

    // ================= sweep 2: write attn, accumulate O =================
    f32x4 oaccA = {0.f, 0.f, 0.f, 0.f};
    f32x4 oaccB = {0.f, 0.f, 0.f, 0.f};
    float* ap0 = attn_out + (size_t)qrow0 * S_ + colbase;

    for (int kt = 0; kt < S_ / KT; ++kt) {
        {
            const float* srck = Kg + ((size_t)(kt * KT + skk)) * D_ + sd0;
            const float4 x0 = *(const float4*)(srck);
            const float4 x1 = *(const float4*)(srck + 4);
            f16x8 o;
            o[0] = (f16)x0.x; o[1] = (f16)x0.y; o[2] = (f16)x0.z; o[3] = (f16)x0.w;
            o[4] = (f16)x1.x; o[5] = (f16)x1.y; o[6] = (f16)x1.z; o[7] = (f16)x1.w;
            *(f16x8*)&Ksh[skk][sd0] = o;

            const float* srcv = Vg + ((size_t)(kt * KT + skk)) * D_ + sd0;
            const float4 y0 = *(const float4*)(srcv);
            const float4 y1 = *(const float4*)(srcv + 4);
            f16x2 p01, p23, p45, p67;
            p01[0] = (f16)y0.x; p01[1] = (f16)y0.y;
            p23[0] = (f16)y0.z; p23[1] = (f16)y0.w;
            p45[0] = (f16)y1.x; p45[1] = (f16)y1.y;
            p67[0] = (f16)y1.z; p67[1] = (f16)y1.w;
            *(f16x2*)&Vsh[skk][sd0]     = p01;
            *(f16x2*)&Vsh[skk][sd0 + 2] = p23;
            *(f16x2*)&Vsh[skk][sd0 + 4] = p45;
            *(f16x2*)&Vsh[skk][sd0 + 6] = p67;
        }
        __syncthreads();
        // scores (recompute), both 16-col blocks
        const f16x8 b0a = *(const f16x8*)&Ksh[colbase][quad * 8];
        const f16x8 b0b = *(const f16x8*)&Ksh[colbase][32 + quad * 8];
        const f16x8 b1a = *(const f16x8*)&Ksh[32 + colbase][quad * 8];
        const f16x8 b1b = *(const f16x8*)&Ksh[32 + colbase][32 + quad * 8];
        f32x4 c0 = {0.f, 0.f, 0.f, 0.f};
        c0 = MFMA16(a0, b0a, c0);
        c0 = MFMA16(a1, b0b, c0);
        f32x4 c1 = {0.f, 0.f, 0.f, 0.f};
        c1 = MFMA16(a0, b1a, c1);
        c1 = MFMA16(a1, b1b, c1);
        const int* mp = mp0 + kt * KT;
        float* ap = ap0 + kt * KT;
#pragma unroll
        for (int r = 0; r < 4; ++r) {
            const int m0 = mp[(size_t)r * S_];
            const int m1 = mp[(size_t)r * S_ + 32];
            const float e0 = (m0 == 1) ? 0.f : __expf(c0[r]);
            const float e1 = (m1 == 1) ? 0.f : __expf(c1[r]);
            const float p0 = e0 * rlq[r];
            const float p1 = e1 * rlq[r];
            ap[(size_t)r * S_]      = p0;           // attn output
            ap[(size_t)r * S_ + 32] = p1;
            Psh[qrow0 + r][colbase]      = (f16)p0; // C-layout -> A-layout via LDS
            Psh[qrow0 + r][colbase + 32] = (f16)p1;
        }
        __syncthreads();
        // PV: wave tile (qi rows; d-cols colbase and colbase+32)
        const f16x8 pa0 = *(const f16x8*)&Psh[qi * 16 + l16][quad * 8];
        const f16x8 pa1 = *(const f16x8*)&Psh[qi * 16 + l16][32 + quad * 8];
        f16x8 vb0a, vb1a, vb0b, vb1b;
        const int dcolA = colbase;
        const int dcolB = colbase + 32;
#pragma unroll
        for (int j = 0; j < 8; ++j) {
            vb0a[j] = Vsh[quad * 8 + j][dcolA];
            vb1a[j] = Vsh[32 + quad * 8 + j][dcolA];
            vb0b[j] = Vsh[quad * 8 + j][dcolB];
            vb1b[j] = Vsh[32 + quad * 8 + j][dcolB];
        }
        oaccA = MFMA16(pa0, vb0a, oaccA);
        oaccA = MFMA16(pa1, vb1a, oaccA);
        oaccB = MFMA16(pa0, vb0b, oaccB);
        oaccB = MFMA16(pa1, vb1b, oaccB);
        __syncthreads();
    }

    // res: rows qrow0+r, cols colbase and colbase+32 (1/l folded into P)
#pragma unroll
    for (int r = 0; r < 4; ++r) {
        res_out[(size_t)(qrow0 + r) * D_ + colbase]      = oaccA[r];
        res_out[(size_t)(qrow0 + r) * D_ + colbase + 32] = oaccB[r];
    }
}

extern "C" void kernel_launch(void* const* d_in, const int* in_sizes, int n_in,
                              void* d_out, int out_size, void* d_ws, size_t ws_size,
                              hipStream_t stream) {
    (void)in_sizes; (void)n_in; (void)out_size; (void)d_ws; (void)ws_size;
    const float* q   = (const float*)d_in[0];
    const float* k   = (const float*)d_in[1];
    const float* v   = (const float*)d_in[2];
    const int*  mask = (const int*)d_in[3];
    float* out = (float*)d_out;
    dim3 grid(S_ / QB, H_, B_);   // 32 x 16 x 2 = 1024 = 4 blocks/CU exactly, no tail
    attn_kernel<<<grid, dim3(NTHREADS), 0, stream>>>(q, k, v, mask, out);
}